// Round 1
// baseline (4603.272 us; speedup 1.0000x reference)
//
#include <hip/hip_runtime.h>
#include <math.h>

#define T_TOK 16384
#define D_DIM 1024
#define E_EXP 48
#define S_SH 4
#define M_DIM 1024
#define N1 4096      // S*M
#define K_OUT 256    // D/S
#define CAP 512

__device__ inline unsigned f2ord(float f) {
  unsigned u = __float_as_uint(f);
  return (u & 0x80000000u) ? ~u : (u | 0x80000000u);
}

__device__ inline unsigned short f2bf(float f) {
  unsigned u = __float_as_uint(f);
  unsigned r = (u + 0x7fffu + ((u >> 16) & 1u)) >> 16;
  return (unsigned short)r;
}
__device__ inline float bf2f(unsigned short h) {
  return __uint_as_float(((unsigned)h) << 16);
}
__device__ inline float gelu_exact(float v) {
  return 0.5f * v * (1.0f + erff(v * 0.7071067811865476f));
}

// ---------------- Router: logitsT[E][T] = (x @ Wr^T)^T, fp64 accumulate ---------
__global__ __launch_bounds__(256) void router_kernel(
    const float* __restrict__ x, const float* __restrict__ Wr,
    float* __restrict__ logitsT) {
  __shared__ float xs[32][129];
  __shared__ float wsh[48][129];
  int t0 = blockIdx.x * 32;
  int tid = threadIdx.x;
  double acc[6];
#pragma unroll
  for (int q = 0; q < 6; q++) acc[q] = 0.0;
  for (int d0 = 0; d0 < D_DIM; d0 += 128) {
    for (int i = tid; i < 32 * 128; i += 256)
      xs[i >> 7][i & 127] = x[(size_t)(t0 + (i >> 7)) * D_DIM + d0 + (i & 127)];
    for (int i = tid; i < 48 * 128; i += 256)
      wsh[i >> 7][i & 127] = Wr[(size_t)(i >> 7) * D_DIM + d0 + (i & 127)];
    __syncthreads();
#pragma unroll
    for (int q = 0; q < 6; q++) {
      int p = tid + 256 * q;
      int t = p & 31, e = p >> 5;
      double a = 0.0;
      for (int d = 0; d < 128; d++) a += (double)xs[t][d] * (double)wsh[e][d];
      acc[q] += a;
    }
    __syncthreads();
  }
  for (int q = 0; q < 6; q++) {
    int p = tid + 256 * q;
    int t = p & 31, e = p >> 5;
    logitsT[(size_t)e * T_TOK + t0 + t] = (float)acc[q];
  }
}

// ---------------- Top-512 per expert (radix select) + softmax -------------------
__global__ __launch_bounds__(256) void topk_kernel(
    const float* __restrict__ logitsT, int* __restrict__ idx_sel,
    float* __restrict__ w_sel) {
  int e = blockIdx.x;
  const float* lg = logitsT + (size_t)e * T_TOK;
  __shared__ unsigned hist[256];
  __shared__ unsigned sh_prefix;
  __shared__ int sh_kneed;
  __shared__ int cnt_gt, cnt_eq;
  __shared__ int eq_idx[256];
  __shared__ float red[256];
  int tid = threadIdx.x;
  unsigned prefix = 0;
  int kneed = CAP;
  for (int shift = 24; shift >= 0; shift -= 8) {
    hist[tid] = 0;
    __syncthreads();
    for (int t = tid; t < T_TOK; t += 256) {
      unsigned u = f2ord(lg[t]);
      bool ok = (shift == 24) || ((u >> (shift + 8)) == prefix);
      if (ok) atomicAdd(&hist[(u >> shift) & 255u], 1u);
    }
    __syncthreads();
    if (tid == 0) {
      int k = kneed;
      unsigned b = 255;
      for (;; b--) {
        int c = (int)hist[b];
        if (k <= c || b == 0) break;
        k -= c;
      }
      sh_prefix = (prefix << 8) | b;
      sh_kneed = k;
      cnt_gt = 0;
      cnt_eq = 0;
    }
    __syncthreads();
    prefix = sh_prefix;
    kneed = sh_kneed;
    __syncthreads();
  }
  unsigned pivot = prefix;
  for (int t = tid; t < T_TOK; t += 256) {
    unsigned u = f2ord(lg[t]);
    if (u > pivot) {
      int p = atomicAdd(&cnt_gt, 1);
      idx_sel[e * CAP + p] = t;
    } else if (u == pivot) {
      int p = atomicAdd(&cnt_eq, 1);
      if (p < 256) eq_idx[p] = t;
    }
  }
  __syncthreads();
  if (tid == 0) {
    int base = cnt_gt;  // == CAP - kneed
    int ne = cnt_eq < 256 ? cnt_eq : 256;
    for (int s = 0; s < kneed; s++) {
      int best = 0x7fffffff, bj = -1;
      for (int j = 0; j < ne; j++) {
        int v = eq_idx[j];
        if (v >= 0 && v < best) { best = v; bj = j; }
      }
      if (bj >= 0) eq_idx[bj] = -1; else best = 0;
      idx_sel[e * CAP + base + s] = best;
    }
  }
  __syncthreads();
  // softmax over selected values
  float vmax = -INFINITY;
  for (int s = tid; s < CAP; s += 256) vmax = fmaxf(vmax, lg[idx_sel[e * CAP + s]]);
  red[tid] = vmax;
  __syncthreads();
  for (int o = 128; o > 0; o >>= 1) {
    if (tid < o) red[tid] = fmaxf(red[tid], red[tid + o]);
    __syncthreads();
  }
  vmax = red[0];
  __syncthreads();
  float lsum = 0.f;
  for (int s = tid; s < CAP; s += 256) lsum += expf(lg[idx_sel[e * CAP + s]] - vmax);
  red[tid] = lsum;
  __syncthreads();
  for (int o = 128; o > 0; o >>= 1) {
    if (tid < o) red[tid] += red[tid + o];
    __syncthreads();
  }
  float denom = red[0];
  for (int s = tid; s < CAP; s += 256)
    w_sel[e * CAP + s] = expf(lg[idx_sel[e * CAP + s]] - vmax) / denom;
}

// ---------------- GEMM1: H[e][c][n] = gelu(x[idx] @ W1[e]) , bf16 out -----------
// per expert: [512 x 1024] @ [1024 x 4096]; 64x64 tiles, 256 thr, 4x4 microtile
__global__ __launch_bounds__(256) void gemm1_kernel(
    const float* __restrict__ x, const float* __restrict__ W1,
    const float* __restrict__ b1, const int* __restrict__ idx_sel,
    unsigned short* __restrict__ H, int e0) {
  int bid = blockIdx.x;
  int e_local = bid >> 9;
  int rem = bid & 511;
  int ntile = rem & 63;
  int ctile = rem >> 6;
  int e = e0 + e_local;
  int n0 = ntile << 6;
  int s = n0 >> 10;
  int m0 = n0 & 1023;
  int c0 = ctile << 6;
  __shared__ float As[16][68];
  __shared__ float Bs[16][68];
  __shared__ int toks[64];
  int tid = threadIdx.x;
  int tx = tid & 15, ty = tid >> 4;
  if (tid < 64) toks[tid] = idx_sel[e * CAP + c0 + tid];
  __syncthreads();
  int ar = tid & 63, ak = (tid >> 6) << 2;
  const float* xrow = x + (size_t)toks[ar] * D_DIM;
  int bd = tid >> 4, bc = (tid & 15) << 2;
  const float* W1p = W1 + (size_t)(e * S_SH + s) * D_DIM * M_DIM;
  float acc[4][4] = {{0.f}};
  for (int k0 = 0; k0 < D_DIM; k0 += 16) {
    float4 av = *(const float4*)(xrow + k0 + ak);
    As[ak + 0][ar] = av.x;
    As[ak + 1][ar] = av.y;
    As[ak + 2][ar] = av.z;
    As[ak + 3][ar] = av.w;
    *(float4*)&Bs[bd][bc] = *(const float4*)(W1p + (size_t)(k0 + bd) * M_DIM + m0 + bc);
    __syncthreads();
#pragma unroll
    for (int k = 0; k < 16; k++) {
      float4 a4 = *(const float4*)&As[k][ty << 2];
      float4 b4 = *(const float4*)&Bs[k][tx << 2];
      float a[4] = {a4.x, a4.y, a4.z, a4.w};
      float b[4] = {b4.x, b4.y, b4.z, b4.w};
#pragma unroll
      for (int i = 0; i < 4; i++)
#pragma unroll
        for (int j = 0; j < 4; j++) acc[i][j] += a[i] * b[j];
    }
    __syncthreads();
  }
  const float* b1p = b1 + (size_t)(e * S_SH + s) * M_DIM + m0 + (tx << 2);
  float bb[4] = {b1p[0], b1p[1], b1p[2], b1p[3]};
#pragma unroll
  for (int i = 0; i < 4; i++) {
    int row = (ty << 2) + i;
    size_t base = ((size_t)e_local * CAP + c0 + row) * N1 + n0 + (tx << 2);
    ushort4 st;
    st.x = f2bf(gelu_exact(acc[i][0] + bb[0]));
    st.y = f2bf(gelu_exact(acc[i][1] + bb[1]));
    st.z = f2bf(gelu_exact(acc[i][2] + bb[2]));
    st.w = f2bf(gelu_exact(acc[i][3] + bb[3]));
    *(ushort4*)(H + base) = st;
  }
}

// ---------------- GEMM2: y = H[e,:,s*1024:+1024] @ W2[e][s] + b2, scatter -------
// per (e,s): [512 x 1024] @ [1024 x 256]; 64x64 tiles
__global__ __launch_bounds__(256) void gemm2_kernel(
    const unsigned short* __restrict__ H, const float* __restrict__ W2,
    const float* __restrict__ b2, const int* __restrict__ idx_sel,
    const float* __restrict__ w_sel, float* __restrict__ out, int e0) {
  int bid = blockIdx.x;
  int e_local = bid >> 7;
  int rem = bid & 127;
  int ctile = rem & 7;
  int rest = rem >> 3;  // 0..15
  int s = rest >> 2;
  int ktile = rest & 3;
  int e = e0 + e_local;
  int c0 = ctile << 6;
  int kt0 = ktile << 6;
  __shared__ float As[16][68];
  __shared__ float Bs[16][68];
  __shared__ int toks[64];
  __shared__ float wts[64];
  int tid = threadIdx.x;
  int tx = tid & 15, ty = tid >> 4;
  if (tid < 64) {
    toks[tid] = idx_sel[e * CAP + c0 + tid];
    wts[tid] = w_sel[e * CAP + c0 + tid];
  }
  __syncthreads();
  int ar = tid & 63, ak = (tid >> 6) << 2;
  const unsigned short* hrow =
      H + ((size_t)e_local * CAP + c0 + ar) * N1 + ((size_t)s << 10);
  int bd = tid >> 4, bc = (tid & 15) << 2;
  const float* W2p = W2 + (size_t)(e * S_SH + s) * M_DIM * K_OUT;
  float acc[4][4] = {{0.f}};
  for (int k0 = 0; k0 < M_DIM; k0 += 16) {
    ushort4 av = *(const ushort4*)(hrow + k0 + ak);
    As[ak + 0][ar] = bf2f(av.x);
    As[ak + 1][ar] = bf2f(av.y);
    As[ak + 2][ar] = bf2f(av.z);
    As[ak + 3][ar] = bf2f(av.w);
    *(float4*)&Bs[bd][bc] = *(const float4*)(W2p + (size_t)(k0 + bd) * K_OUT + kt0 + bc);
    __syncthreads();
#pragma unroll
    for (int k = 0; k < 16; k++) {
      float4 a4 = *(const float4*)&As[k][ty << 2];
      float4 b4 = *(const float4*)&Bs[k][tx << 2];
      float a[4] = {a4.x, a4.y, a4.z, a4.w};
      float b[4] = {b4.x, b4.y, b4.z, b4.w};
#pragma unroll
      for (int i = 0; i < 4; i++)
#pragma unroll
        for (int j = 0; j < 4; j++) acc[i][j] += a[i] * b[j];
    }
    __syncthreads();
  }
  const float* b2p = b2 + (size_t)(e * S_SH + s) * K_OUT + kt0 + (tx << 2);
  float bb[4] = {b2p[0], b2p[1], b2p[2], b2p[3]};
#pragma unroll
  for (int i = 0; i < 4; i++) {
    int row = (ty << 2) + i;
    int token = toks[row];
    float wt = wts[row];
    float* orow = out + (size_t)token * D_DIM + (s << 8) + kt0 + (tx << 2);
#pragma unroll
    for (int j = 0; j < 4; j++) {
      float yv = (acc[i][j] + bb[j]) * wt;
      unsafeAtomicAdd(orow + j, yv);
    }
  }
}

extern "C" void kernel_launch(void* const* d_in, const int* in_sizes, int n_in,
                              void* d_out, int out_size, void* d_ws, size_t ws_size,
                              hipStream_t stream) {
  const float* x = (const float*)d_in[0];
  const float* Wr = (const float*)d_in[1];
  const float* W1 = (const float*)d_in[2];
  const float* b1 = (const float*)d_in[3];
  const float* W2 = (const float*)d_in[4];
  const float* b2 = (const float*)d_in[5];
  float* out = (float*)d_out;

  char* wsb = (char*)d_ws;
  float* logitsT = (float*)wsb;                      // 48*16384*4 = 3,145,728 B
  int* idx_sel = (int*)(wsb + 3145728);              // 48*512*4   =    98,304 B
  float* w_sel = (float*)(wsb + 3244032);            // 48*512*4   =    98,304 B
  unsigned short* H = (unsigned short*)(wsb + 3342336);
  size_t h_per_e = (size_t)CAP * N1 * sizeof(unsigned short);  // 4 MiB
  long long avail = (long long)ws_size - 3342336LL;
  int chunk = (int)(avail / (long long)h_per_e);
  if (chunk < 1) chunk = 1;
  if (chunk > E_EXP) chunk = E_EXP;

  hipMemsetAsync(d_out, 0, (size_t)T_TOK * D_DIM * sizeof(float), stream);
  router_kernel<<<T_TOK / 32, 256, 0, stream>>>(x, Wr, logitsT);
  topk_kernel<<<E_EXP, 256, 0, stream>>>(logitsT, idx_sel, w_sel);
  for (int ee = 0; ee < E_EXP; ee += chunk) {
    int ne = (chunk < E_EXP - ee) ? chunk : (E_EXP - ee);
    gemm1_kernel<<<ne * 512, 256, 0, stream>>>(x, W1, b1, idx_sel, H, ee);
    gemm2_kernel<<<ne * 128, 256, 0, stream>>>(H, W2, b2, idx_sel, w_sel, out, ee);
  }
}